// Round 4
// baseline (335.830 us; speedup 1.0000x reference)
//
#include <hip/hip_runtime.h>
#include <hip/hip_bf16.h>

#define NNODE 512
#define CCH   16
#define TT    15
#define TP    16
#define HH    32
#define DD    32

typedef unsigned short u16;
typedef unsigned int   u32;
typedef short bf8 __attribute__((ext_vector_type(8)));   // 8 bf16 = 4 VGPR (MFMA A/B frag)
typedef float f4  __attribute__((ext_vector_type(4)));   // MFMA C/D frag

__device__ __forceinline__ float bf2f(u16 v) {
    union { u32 u; float f; } x; x.u = ((u32)v) << 16; return x.f;
}
__device__ __forceinline__ u16 f2bf(float f) {
    union { float f; u32 u; } x; x.f = f;
    u32 u = x.u;
    return (u16)((u + 0x7FFFu + ((u >> 16) & 1u)) >> 16);
}
__device__ __forceinline__ void unpack8(uint4 p, float* o) {
    o[0]=bf2f((u16)(p.x & 0xffffu)); o[1]=bf2f((u16)(p.x >> 16));
    o[2]=bf2f((u16)(p.y & 0xffffu)); o[3]=bf2f((u16)(p.y >> 16));
    o[4]=bf2f((u16)(p.z & 0xffffu)); o[5]=bf2f((u16)(p.z >> 16));
    o[6]=bf2f((u16)(p.w & 0xffffu)); o[7]=bf2f((u16)(p.w >> 16));
}
__device__ __forceinline__ uint4 pack8(const u16* v) {
    return make_uint4((u32)v[0]|((u32)v[1]<<16), (u32)v[2]|((u32)v[3]<<16),
                      (u32)v[4]|((u32)v[5]<<16), (u32)v[6]|((u32)v[7]<<16));
}

// ---------------------------------------------------------------------------
// K1: blocks 0..511: per-node prep. blocks 512..767: adjacency tiles.
//     blocks 768..896: zero temp/u1/v2/counters (for the fused atomics).
// ---------------------------------------------------------------------------
__global__ __launch_bounds__(256) void k_prep_adjp(
    const float* __restrict__ x, const float* __restrict__ W1,
    const float* __restrict__ W2, const float* __restrict__ W3,
    const float* __restrict__ adj,
    u16* __restrict__ A1, u16* __restrict__ B1,
    u16* __restrict__ A2T, u16* __restrict__ B2T,
    u16* __restrict__ Qb, float* __restrict__ QAd, float* __restrict__ QB,
    u16* __restrict__ adjP, u16* __restrict__ adjPT,
    float* __restrict__ temp, float* __restrict__ u1, float* __restrict__ v2,
    u32* __restrict__ ctrs)
{
    int tid = threadIdx.x;
    if (blockIdx.x >= 768) {                 // zero accumulators + counters
        int idx = (blockIdx.x - 768) * 256 + tid;
        if (idx < 16384) temp[idx] = 0.f;
        else if (idx < 24576) u1[idx - 16384] = 0.f;
        else if (idx < 32768) v2[idx - 24576] = 0.f;
        else if (idx < 32864) ctrs[idx - 32768] = 0u;
        return;
    }
    if (blockIdx.x < 512) {
        int n = blockIdx.x;
        __shared__ alignas(16) float xs[CCH];
        __shared__ alignas(16) float A1row[512], B1row[512];
        __shared__ alignas(16) float A2row[512], B2row[512];
        __shared__ alignas(16) float Qs[HH];
        if (tid < CCH) xs[tid] = x[n*CCH + tid];
        __syncthreads();
        float xr[CCH];
        #pragma unroll
        for (int i=0;i<CCH;i++) xr[i]=xs[i];
        #pragma unroll
        for (int rep=0; rep<2; rep++) {
            int c = tid + rep*256;
            float a1=0.f,b1=0.f,a2=0.f,b2=0.f;
            #pragma unroll
            for (int i=0;i<CCH;i++) {
                a1 += xr[i]*W1[i*512 + c];
                b1 += xr[i]*W1[(CCH+i)*512 + c];
                a2 += xr[i]*W2[i*512 + c];
                b2 += xr[i]*W2[(CCH+i)*512 + c];
            }
            A1[(size_t)n*512 + c]=f2bf(a1); B1[(size_t)n*512 + c]=f2bf(b1);
            A1row[c]=a1; B1row[c]=b1; A2row[c]=a2; B2row[c]=b2;
        }
        if (tid < HH) {
            float q=0.f;
            #pragma unroll
            for (int i=0;i<CCH;i++) q += xr[i]*W3[i*HH + tid];
            Qs[tid]=q; Qb[(size_t)n*HH + tid]=f2bf(q);
        }
        __syncthreads();
        if (tid < TP) {
            float qa=0.f, qb=0.f;
            #pragma unroll
            for (int h=0;h<HH;h++) { qa += Qs[h]*A1row[tid*HH+h]; qb += Qs[h]*B1row[tid*HH+h]; }
            QAd[(size_t)n*TP + tid]=qa; QB[(size_t)n*TP + tid]=qb;
        }
        {   // A2T/B2T: [d][n*16+t]; coalesced u32 stores
            int d = tid >> 3, t0 = (tid & 7) * 2;
            u32 pa = (u32)f2bf(A2row[t0*32 + d]) | ((u32)f2bf(A2row[(t0+1)*32 + d]) << 16);
            u32 pb = (u32)f2bf(B2row[t0*32 + d]) | ((u32)f2bf(B2row[(t0+1)*32 + d]) << 16);
            *(u32*)(A2T + (size_t)d*8192 + n*16 + t0) = pa;
            *(u32*)(B2T + (size_t)d*8192 + n*16 + t0) = pb;
        }
    } else {
        int b = blockIdx.x - 512;            // 0..255
        int n0 = (b >> 4) * 32, m0 = (b & 15) * 32;
        __shared__ alignas(16) u16 s[32*520];  // stride 520 (1040B=65*16)
        #pragma unroll
        for (int i = 0; i < 60; i++) {
            int e = tid + i*256;
            int nl = e / 480; int rem = e - nl*480;
            int ml = rem / 15; int t = rem - ml*15;
            float v = adj[((size_t)(n0+nl)*512 + (m0+ml))*TT + t];
            s[nl*520 + ml*16 + t] = f2bf(v);
        }
        #pragma unroll
        for (int i = 0; i < 4; i++) {
            int e = tid + i*256; int nl = e >> 5, ml = e & 31;
            s[nl*520 + ml*16 + 15] = ((n0+nl) == (m0+ml)) ? (u16)0x3F80 : (u16)0;
        }
        __syncthreads();
        #pragma unroll
        for (int i = 0; i < 8; i++) {        // adjP: 32 rows x 1KB
            int c = tid + i*256;
            int nl = c >> 6, off = (c & 63) * 8;
            uint4 vv = *(const uint4*)(s + nl*520 + off);
            *(uint4*)(adjP + (size_t)(n0+nl)*8192 + m0*16 + off) = vv;
        }
        #pragma unroll
        for (int i = 0; i < 8; i++) {        // adjPT: 32 rows x 1KB (transposed)
            int c = tid + i*256;
            int ml = c >> 6, nlh = c & 63, nl = nlh >> 1, half = nlh & 1;
            uint4 vv = *(const uint4*)(s + nl*520 + ml*16 + half*8);
            *(uint4*)(adjPT + (size_t)(m0+ml)*8192 + (n0+nl)*16 + half*8) = vv;
        }
    }
}

// ---------------------------------------------------------------------------
// K2: fused logits (swapped-operand MFMA) + FUSED softmax stats:
// last block per row-panel (via device atomic counter) computes the stats.
// ---------------------------------------------------------------------------
__global__ __launch_bounds__(256) void k_logits(
    const u16* __restrict__ Qb, const u16* __restrict__ A1, const u16* __restrict__ B1,
    const u16* __restrict__ adjP, const u16* __restrict__ adjPT,
    const float* __restrict__ QAd, const float* __restrict__ QB,
    float* __restrict__ L1, float* __restrict__ L2T,
    float2* __restrict__ stats, u32* __restrict__ ctrN, u32* __restrict__ ctrM)
{
    const int m0 = blockIdx.x * 16, n0 = blockIdx.y * 16;
    const int tid = threadIdx.x;
    const int wv = tid >> 6, lane = tid & 63, l15 = lane & 15, quad = lane >> 4;
    __shared__ alignas(16) float sL1[16*17];
    __shared__ alignas(16) float sL2[16*17];

    bf8 qbN = *(const bf8*)(Qb + (size_t)(n0 + l15)*32 + quad*8);
    bf8 qbM = *(const bf8*)(Qb + (size_t)(m0 + l15)*32 + quad*8);
    float4 qb4 = *(const float4*)(QB  + (size_t)(n0 + l15)*TP + quad*4);
    float4 qa4 = *(const float4*)(QAd + (size_t)(m0 + l15)*TP + quad*4);

    #pragma unroll
    for (int j = 0; j < 4; j++) {
        int m = m0 + wv*4 + j;
        bf8 aA1 = *(const bf8*)(A1 + (size_t)m*512 + l15*32 + quad*8);
        f4 z = {0.f,0.f,0.f,0.f};
        f4 g = __builtin_amdgcn_mfma_f32_16x16x32_bf16(aA1, qbN, z, 0, 0, 0);
        uint2 ax = *(const uint2*)(adjPT + (size_t)m*8192 + (n0 + l15)*16 + quad*4);
        uint2 ay = *(const uint2*)(adjP  + (size_t)m*8192 + (n0 + l15)*16 + quad*4);
        float v;
        v = bf2f((u16)(ax.x & 0xffffu)) * g[0];
        v = fmaf(bf2f((u16)(ax.x >> 16)),     g[1], v);
        v = fmaf(bf2f((u16)(ax.y & 0xffffu)), g[2], v);
        v = fmaf(bf2f((u16)(ax.y >> 16)),     g[3], v);
        v = fmaf(bf2f((u16)(ay.x & 0xffffu)), qb4.x, v);
        v = fmaf(bf2f((u16)(ay.x >> 16)),     qb4.y, v);
        v = fmaf(bf2f((u16)(ay.y & 0xffffu)), qb4.z, v);
        v = fmaf(bf2f((u16)(ay.y >> 16)),     qb4.w, v);
        v += __shfl_xor(v, 16, 64);
        v += __shfl_xor(v, 32, 64);
        if (quad == 0) sL1[l15*17 + wv*4 + j] = v;
    }
    #pragma unroll
    for (int j = 0; j < 4; j++) {
        int n = n0 + wv*4 + j;
        bf8 aB1 = *(const bf8*)(B1 + (size_t)n*512 + l15*32 + quad*8);
        f4 z = {0.f,0.f,0.f,0.f};
        f4 h = __builtin_amdgcn_mfma_f32_16x16x32_bf16(aB1, qbM, z, 0, 0, 0);
        uint2 ax = *(const uint2*)(adjPT + (size_t)n*8192 + (m0 + l15)*16 + quad*4);
        uint2 ay = *(const uint2*)(adjP  + (size_t)n*8192 + (m0 + l15)*16 + quad*4);
        float v;
        v = bf2f((u16)(ax.x & 0xffffu)) * h[0];
        v = fmaf(bf2f((u16)(ax.x >> 16)),     h[1], v);
        v = fmaf(bf2f((u16)(ax.y & 0xffffu)), h[2], v);
        v = fmaf(bf2f((u16)(ax.y >> 16)),     h[3], v);
        v = fmaf(bf2f((u16)(ay.x & 0xffffu)), qa4.x, v);
        v = fmaf(bf2f((u16)(ay.x >> 16)),     qa4.y, v);
        v = fmaf(bf2f((u16)(ay.y & 0xffffu)), qa4.z, v);
        v = fmaf(bf2f((u16)(ay.y >> 16)),     qa4.w, v);
        v += __shfl_xor(v, 16, 64);
        v += __shfl_xor(v, 32, 64);
        if (quad == 0) sL2[l15*17 + wv*4 + j] = v;
    }
    __syncthreads();
    int row = tid >> 4, col = tid & 15;
    L1 [(size_t)(n0+row)*NNODE + m0 + col] = sL1[row*17+col];
    L2T[(size_t)(m0+row)*NNODE + n0 + col] = sL2[row*17+col];

    // ---- fused stats: release (fence+count), last block acquires & reduces ----
    __threadfence();
    __shared__ int doN, doM;
    if (tid == 0) {
        doN = (atomicAdd(&ctrN[blockIdx.y], 1u) == 31u) ? 1 : 0;
        doM = (atomicAdd(&ctrM[blockIdx.x], 1u) == 31u) ? 1 : 0;
    }
    __syncthreads();
    if (doN) {
        __threadfence();
        #pragma unroll
        for (int rr = 0; rr < 4; rr++) {
            int r = n0 + wv*4 + rr;
            const float* rw = L1 + (size_t)r*NNODE;
            float4 a = *(const float4*)(rw + lane*8);
            float4 b = *(const float4*)(rw + lane*8 + 4);
            float mx = fmaxf(fmaxf(fmaxf(a.x,a.y),fmaxf(a.z,a.w)),
                             fmaxf(fmaxf(b.x,b.y),fmaxf(b.z,b.w)));
            #pragma unroll
            for (int o=32; o; o>>=1) mx = fmaxf(mx, __shfl_xor(mx, o, 64));
            float sm = __expf(a.x-mx)+__expf(a.y-mx)+__expf(a.z-mx)+__expf(a.w-mx)
                     + __expf(b.x-mx)+__expf(b.y-mx)+__expf(b.z-mx)+__expf(b.w-mx);
            #pragma unroll
            for (int o=32; o; o>>=1) sm += __shfl_xor(sm, o, 64);
            if (lane == 0) { float2 st; st.x = mx; st.y = 1.0f/sm; stats[r] = st; }
        }
    }
    if (doM) {
        __threadfence();
        #pragma unroll
        for (int rr = 0; rr < 4; rr++) {
            int r = m0 + wv*4 + rr;
            const float* rw = L2T + (size_t)r*NNODE;
            float4 a = *(const float4*)(rw + lane*8);
            float4 b = *(const float4*)(rw + lane*8 + 4);
            float mx = fmaxf(fmaxf(fmaxf(a.x,a.y),fmaxf(a.z,a.w)),
                             fmaxf(fmaxf(b.x,b.y),fmaxf(b.z,b.w)));
            #pragma unroll
            for (int o=32; o; o>>=1) mx = fmaxf(mx, __shfl_xor(mx, o, 64));
            float sm = __expf(a.x-mx)+__expf(a.y-mx)+__expf(a.z-mx)+__expf(a.w-mx)
                     + __expf(b.x-mx)+__expf(b.y-mx)+__expf(b.z-mx)+__expf(b.w-mx);
            #pragma unroll
            for (int o=32; o; o>>=1) sm += __shfl_xor(sm, o, 64);
            if (lane == 0) { float2 st; st.x = mx; st.y = 1.0f/sm; stats[NNODE + r] = st; }
        }
    }
}

// ---------------------------------------------------------------------------
// K34: W-chunk build (LDS, XOR-swizzled) + MFMA GEMM + u-fold, accumulated
// via f32 atomics; FUSED finalize: last block per j0 (64 contributors) adds
// self terms + lrelu and writes out. Atomic data read back via atomicAdd(p,0)
// so reads stay on the atomic coherence path.
// ---------------------------------------------------------------------------
__global__ __launch_bounds__(256) void k_smx_gemm(
    const float* __restrict__ L1, const float* __restrict__ L2T,
    const u16* __restrict__ adjP, const u16* __restrict__ adjPT,
    const u16* __restrict__ A2T, const u16* __restrict__ B2T,
    const float2* __restrict__ stats,
    float* __restrict__ temp, float* __restrict__ u1, float* __restrict__ v2,
    u32* __restrict__ ctrJ, float* __restrict__ out)
{
    const int j0 = blockIdx.x * 16, kc = blockIdx.y, dir = blockIdx.z;
    const int tid = threadIdx.x;
    const int wv = tid >> 6, lane = tid & 63, l15 = lane & 15, quad = lane >> 4;
    const float* Lbase = dir ? L2T : L1;

    __shared__ alignas(16) u16 Wt[16*256];      // 8KB: W chunk, 16B-slot XOR swizzle
    __shared__ alignas(16) float redb[4][512];  // 8KB: cross-wave MFMA reduce
    __shared__ float2 sst[16];

    if (tid < 16) sst[tid] = stats[dir*NNODE + j0 + tid];
    __syncthreads();

    // ---- phase 1: W-chunk build + u partial (1 m-column per thread) ----
    {
        int j = tid >> 4, cb = tid & 15;
        int m = kc*16 + cb;                   // global m-column
        float2 st = sst[j];
        float s0 = __expf(Lbase[(size_t)(j0+j)*NNODE + m] - st.x) * st.y;

        const uint4* pp = (const uint4*)(adjP + (size_t)(j0+j)*8192 + m*16);
        float av[16]; unpack8(pp[0], av); unpack8(pp[1], av+8);
        u16 wo[16];
        #pragma unroll
        for (int e=0;e<16;e++) wo[e] = f2bf(s0*av[e]);
        #pragma unroll
        for (int q=0;q<2;q++) {
            int sl = (cb*2 + q) ^ (j & 7);    // swizzled 16B slot (32 slots/row)
            *(uint4*)&Wt[j*256 + sl*8] = pack8(wo + q*8);
        }

        const uint4* qq = (const uint4*)(adjPT + (size_t)(j0+j)*8192 + m*16);
        float tv[16]; unpack8(qq[0], tv); unpack8(qq[1], tv+8);
        float ut[16];
        #pragma unroll
        for (int t=0;t<16;t++) ut[t] = s0*tv[t];
        // exchange-and-halve fold over the 16 cb-lanes (xor 1,2,4,8)
        #pragma unroll
        for (int i=0;i<8;i++) {
            float v0 = (lane&1) ? ut[i] : ut[i+8];
            float r0 = __shfl_xor(v0, 1, 64);
            ut[i] = ((lane&1) ? ut[i+8] : ut[i]) + r0;
        }
        #pragma unroll
        for (int i=0;i<4;i++) {
            float v0 = (lane&2) ? ut[i] : ut[i+4];
            float r0 = __shfl_xor(v0, 2, 64);
            ut[i] = ((lane&2) ? ut[i+4] : ut[i]) + r0;
        }
        #pragma unroll
        for (int i=0;i<2;i++) {
            float v0 = (lane&4) ? ut[i] : ut[i+2];
            float r0 = __shfl_xor(v0, 4, 64);
            ut[i] = ((lane&4) ? ut[i+2] : ut[i]) + r0;
        }
        {
            float v0 = (lane&8) ? ut[0] : ut[1];
            float r0 = __shfl_xor(v0, 8, 64);
            ut[0] = ((lane&8) ? ut[1] : ut[0]) + r0;
        }
        int tm = ((cb&1)<<3) | ((cb&2)<<1) | ((cb&4)>>1) | ((cb&8)>>3);
        atomicAdd((dir ? v2 : u1) + (size_t)(j0+j)*TP + tm, ut[0]);
    }
    __syncthreads();

    // ---- phase 2: MFMA [16 j][256 k] x [256 k][32 d]; wave = k-eighth ----
    {
        const u16* Bmat = dir ? B2T : A2T;
        f4 acc0 = {0.f,0.f,0.f,0.f}, acc1 = {0.f,0.f,0.f,0.f};
        #pragma unroll
        for (int st2 = 0; st2 < 2; st2++) {
            int s = wv*2 + st2;               // 0..7
            bf8 afr = *(const bf8*)&Wt[l15*256 + (((s*4 + quad) ^ (l15 & 7)) << 3)];
            bf8 b0 = *(const bf8*)(Bmat + (size_t)(l15)*8192    + kc*256 + s*32 + quad*8);
            bf8 b1 = *(const bf8*)(Bmat + (size_t)(16+l15)*8192 + kc*256 + s*32 + quad*8);
            acc0 = __builtin_amdgcn_mfma_f32_16x16x32_bf16(afr, b0, acc0, 0, 0, 0);
            acc1 = __builtin_amdgcn_mfma_f32_16x16x32_bf16(afr, b1, acc1, 0, 0, 0);
        }
        #pragma unroll
        for (int r = 0; r < 4; r++) {
            redb[wv][      (quad*4+r)*16 + l15] = acc0[r];
            redb[wv][256 + (quad*4+r)*16 + l15] = acc1[r];
        }
    }
    __syncthreads();
    #pragma unroll
    for (int h = 0; h < 2; h++) {
        int o = tid + h*256;                 // 0..511 over (j,d)
        int jj = o >> 5, d = o & 31;
        int idx = (d >> 4)*256 + jj*16 + (d & 15);
        float v = redb[0][idx] + redb[1][idx] + redb[2][idx] + redb[3][idx];
        atomicAdd(&temp[(size_t)(j0 + jj)*DD + d], v);
    }

    // ---- fused finalize: last of the 64 contributing blocks for this j0 ----
    __threadfence();
    __shared__ int doF;
    if (tid == 0) doF = (atomicAdd(&ctrJ[blockIdx.x], 1u) == 63u) ? 1 : 0;
    __syncthreads();
    if (doF) {
        __threadfence();
        __shared__ float uL[256], vL[256];
        uL[tid] = atomicAdd(&u1[(size_t)j0*TP + tid], 0.0f);
        vL[tid] = atomicAdd(&v2[(size_t)j0*TP + tid], 0.0f);
        __syncthreads();
        #pragma unroll
        for (int h = 0; h < 2; h++) {
            int o = tid + h*256;
            int jj = o >> 5, d = o & 31;
            int j = j0 + jj;
            float acc = atomicAdd(&temp[(size_t)j*DD + d], 0.0f);
            const uint4* pb2 = (const uint4*)(B2T + (size_t)d*8192 + j*16);
            const uint4* pa2 = (const uint4*)(A2T + (size_t)d*8192 + j*16);
            float bv[16], avv[16];
            unpack8(pb2[0], bv);  unpack8(pb2[1], bv+8);
            unpack8(pa2[0], avv); unpack8(pa2[1], avv+8);
            #pragma unroll
            for (int t = 0; t < 16; t++)
                acc += uL[jj*16+t]*bv[t] + vL[jj*16+t]*avv[t];
            out[(size_t)j*DD + d] = fmaxf(acc, 0.2f*acc);
        }
    }
}

// ---------------------------------------------------------------------------
extern "C" void kernel_launch(void* const* d_in, const int* in_sizes, int n_in,
                              void* d_out, int out_size, void* d_ws, size_t ws_size,
                              hipStream_t stream)
{
    (void)in_sizes; (void)n_in; (void)out_size; (void)ws_size;
    const float* x   = (const float*)d_in[0];
    const float* adj = (const float*)d_in[1];
    const float* W1  = (const float*)d_in[2];
    const float* W2  = (const float*)d_in[3];
    const float* W3  = (const float*)d_in[4];

    char* ws = (char*)d_ws;
    u16*   adjP  = (u16*)(ws);                   // 8 MB
    u16*   adjPT = (u16*)(ws + 0x800000);        // 8 MB
    u16*   A1    = (u16*)(ws + 0x1000000);       // 512 KB each
    u16*   B1    = (u16*)(ws + 0x1080000);
    u16*   A2T   = (u16*)(ws + 0x1100000);
    u16*   B2T   = (u16*)(ws + 0x1180000);
    u16*   Qb    = (u16*)(ws + 0x1200000);       // 32 KB
    float* QAd   = (float*)(ws + 0x1210000);
    float* QB    = (float*)(ws + 0x1220000);
    float* L1    = (float*)(ws + 0x1300000);     // 1 MB
    float* L2T   = (float*)(ws + 0x1400000);     // 1 MB
    float* temp  = (float*)(ws + 0x1500000);     // 64 KB accumulator
    float* u1    = (float*)(ws + 0x1510000);     // 32 KB
    float* v2    = (float*)(ws + 0x1520000);     // 32 KB
    float2* stats= (float2*)(ws + 0x1530000);    // 8 KB
    u32*   ctrs  = (u32*)  (ws + 0x1540000);     // 96 u32: ctrN[32],ctrM[32],ctrJ[32]
    u32*   ctrN  = ctrs;
    u32*   ctrM  = ctrs + 32;
    u32*   ctrJ  = ctrs + 64;

    k_prep_adjp<<<897, 256, 0, stream>>>(x, W1, W2, W3, adj,
                                         A1, B1, A2T, B2T, Qb, QAd, QB, adjP, adjPT,
                                         temp, u1, v2, ctrs);
    k_logits<<<dim3(32,32), 256, 0, stream>>>(Qb, A1, B1, adjP, adjPT, QAd, QB,
                                              L1, L2T, stats, ctrN, ctrM);
    k_smx_gemm<<<dim3(32,32,2), 256, 0, stream>>>(L1, L2T, adjP, adjPT, A2T, B2T,
                                                  stats, temp, u1, v2, ctrJ,
                                                  (float*)d_out);
}

// Round 5
// 102.180 us; speedup vs baseline: 3.2866x; 3.2866x over previous
//
#include <hip/hip_runtime.h>
#include <hip/hip_bf16.h>

#define NNODE 512
#define CCH   16
#define TT    15
#define TP    16
#define HH    32
#define DD    32

typedef unsigned short u16;
typedef unsigned int   u32;
typedef short bf8 __attribute__((ext_vector_type(8)));   // 8 bf16 = 4 VGPR (MFMA A/B frag)
typedef float f4  __attribute__((ext_vector_type(4)));   // MFMA C/D frag

__device__ __forceinline__ float bf2f(u16 v) {
    union { u32 u; float f; } x; x.u = ((u32)v) << 16; return x.f;
}
__device__ __forceinline__ u16 f2bf(float f) {
    union { float f; u32 u; } x; x.f = f;
    u32 u = x.u;
    return (u16)((u + 0x7FFFu + ((u >> 16) & 1u)) >> 16);
}
__device__ __forceinline__ void unpack8(uint4 p, float* o) {
    o[0]=bf2f((u16)(p.x & 0xffffu)); o[1]=bf2f((u16)(p.x >> 16));
    o[2]=bf2f((u16)(p.y & 0xffffu)); o[3]=bf2f((u16)(p.y >> 16));
    o[4]=bf2f((u16)(p.z & 0xffffu)); o[5]=bf2f((u16)(p.z >> 16));
    o[6]=bf2f((u16)(p.w & 0xffffu)); o[7]=bf2f((u16)(p.w >> 16));
}
__device__ __forceinline__ uint4 pack8(const u16* v) {
    return make_uint4((u32)v[0]|((u32)v[1]<<16), (u32)v[2]|((u32)v[3]<<16),
                      (u32)v[4]|((u32)v[5]<<16), (u32)v[6]|((u32)v[7]<<16));
}

// ---------------------------------------------------------------------------
// K1: blocks 0..511: per-node prep. blocks 512..767: adjacency tiles.
//     blocks 768..895: zero temp/u1/v2 (for k_smx_gemm's atomics). No fences.
// ---------------------------------------------------------------------------
__global__ __launch_bounds__(256) void k_prep_adjp(
    const float* __restrict__ x, const float* __restrict__ W1,
    const float* __restrict__ W2, const float* __restrict__ W3,
    const float* __restrict__ adj,
    u16* __restrict__ A1, u16* __restrict__ B1,
    u16* __restrict__ A2T, u16* __restrict__ B2T,
    u16* __restrict__ Qb, float* __restrict__ QAd, float* __restrict__ QB,
    u16* __restrict__ adjP, u16* __restrict__ adjPT,
    float* __restrict__ temp, float* __restrict__ u1, float* __restrict__ v2)
{
    int tid = threadIdx.x;
    if (blockIdx.x >= 768) {                 // zero accumulators
        int idx = (blockIdx.x - 768) * 256 + tid;
        if (idx < 16384) temp[idx] = 0.f;
        else if (idx < 24576) u1[idx - 16384] = 0.f;
        else if (idx < 32768) v2[idx - 24576] = 0.f;
        return;
    }
    if (blockIdx.x < 512) {
        int n = blockIdx.x;
        __shared__ alignas(16) float xs[CCH];
        __shared__ alignas(16) float A1row[512], B1row[512];
        __shared__ alignas(16) float A2row[512], B2row[512];
        __shared__ alignas(16) float Qs[HH];
        if (tid < CCH) xs[tid] = x[n*CCH + tid];
        __syncthreads();
        float xr[CCH];
        #pragma unroll
        for (int i=0;i<CCH;i++) xr[i]=xs[i];
        #pragma unroll
        for (int rep=0; rep<2; rep++) {
            int c = tid + rep*256;
            float a1=0.f,b1=0.f,a2=0.f,b2=0.f;
            #pragma unroll
            for (int i=0;i<CCH;i++) {
                a1 += xr[i]*W1[i*512 + c];
                b1 += xr[i]*W1[(CCH+i)*512 + c];
                a2 += xr[i]*W2[i*512 + c];
                b2 += xr[i]*W2[(CCH+i)*512 + c];
            }
            A1[(size_t)n*512 + c]=f2bf(a1); B1[(size_t)n*512 + c]=f2bf(b1);
            A1row[c]=a1; B1row[c]=b1; A2row[c]=a2; B2row[c]=b2;
        }
        if (tid < HH) {
            float q=0.f;
            #pragma unroll
            for (int i=0;i<CCH;i++) q += xr[i]*W3[i*HH + tid];
            Qs[tid]=q; Qb[(size_t)n*HH + tid]=f2bf(q);
        }
        __syncthreads();
        if (tid < TP) {
            float qa=0.f, qb=0.f;
            #pragma unroll
            for (int h=0;h<HH;h++) { qa += Qs[h]*A1row[tid*HH+h]; qb += Qs[h]*B1row[tid*HH+h]; }
            QAd[(size_t)n*TP + tid]=qa; QB[(size_t)n*TP + tid]=qb;
        }
        {   // A2T/B2T: [d][n*16+t]; coalesced u32 stores
            int d = tid >> 3, t0 = (tid & 7) * 2;
            u32 pa = (u32)f2bf(A2row[t0*32 + d]) | ((u32)f2bf(A2row[(t0+1)*32 + d]) << 16);
            u32 pb = (u32)f2bf(B2row[t0*32 + d]) | ((u32)f2bf(B2row[(t0+1)*32 + d]) << 16);
            *(u32*)(A2T + (size_t)d*8192 + n*16 + t0) = pa;
            *(u32*)(B2T + (size_t)d*8192 + n*16 + t0) = pb;
        }
    } else {
        int b = blockIdx.x - 512;            // 0..255
        int n0 = (b >> 4) * 32, m0 = (b & 15) * 32;
        __shared__ alignas(16) u16 s[32*520];  // stride 520 (1040B=65*16)
        #pragma unroll
        for (int i = 0; i < 60; i++) {
            int e = tid + i*256;
            int nl = e / 480; int rem = e - nl*480;
            int ml = rem / 15; int t = rem - ml*15;
            float v = adj[((size_t)(n0+nl)*512 + (m0+ml))*TT + t];
            s[nl*520 + ml*16 + t] = f2bf(v);
        }
        #pragma unroll
        for (int i = 0; i < 4; i++) {
            int e = tid + i*256; int nl = e >> 5, ml = e & 31;
            s[nl*520 + ml*16 + 15] = ((n0+nl) == (m0+ml)) ? (u16)0x3F80 : (u16)0;
        }
        __syncthreads();
        #pragma unroll
        for (int i = 0; i < 8; i++) {        // adjP: 32 rows x 1KB
            int c = tid + i*256;
            int nl = c >> 6, off = (c & 63) * 8;
            uint4 vv = *(const uint4*)(s + nl*520 + off);
            *(uint4*)(adjP + (size_t)(n0+nl)*8192 + m0*16 + off) = vv;
        }
        #pragma unroll
        for (int i = 0; i < 8; i++) {        // adjPT: 32 rows x 1KB (transposed)
            int c = tid + i*256;
            int ml = c >> 6, nlh = c & 63, nl = nlh >> 1, half = nlh & 1;
            uint4 vv = *(const uint4*)(s + nl*520 + ml*16 + half*8);
            *(uint4*)(adjPT + (size_t)(m0+ml)*8192 + (n0+nl)*16 + half*8) = vv;
        }
    }
}

// ---------------------------------------------------------------------------
// K2: fused logits (swapped-operand MFMA) + per-panel softmax stats from LDS:
// statsP[row][panel] = (panel max, panel sum-exp). No fences, no atomics.
// ---------------------------------------------------------------------------
__global__ __launch_bounds__(256) void k_logits(
    const u16* __restrict__ Qb, const u16* __restrict__ A1, const u16* __restrict__ B1,
    const u16* __restrict__ adjP, const u16* __restrict__ adjPT,
    const float* __restrict__ QAd, const float* __restrict__ QB,
    float* __restrict__ L1, float* __restrict__ L2T,
    float2* __restrict__ statsP)
{
    const int m0 = blockIdx.x * 16, n0 = blockIdx.y * 16;
    const int tid = threadIdx.x;
    const int wv = tid >> 6, lane = tid & 63, l15 = lane & 15, quad = lane >> 4;
    __shared__ alignas(16) float sL1[16*17];
    __shared__ alignas(16) float sL2[16*17];

    bf8 qbN = *(const bf8*)(Qb + (size_t)(n0 + l15)*32 + quad*8);
    bf8 qbM = *(const bf8*)(Qb + (size_t)(m0 + l15)*32 + quad*8);
    float4 qb4 = *(const float4*)(QB  + (size_t)(n0 + l15)*TP + quad*4);
    float4 qa4 = *(const float4*)(QAd + (size_t)(m0 + l15)*TP + quad*4);

    #pragma unroll
    for (int j = 0; j < 4; j++) {
        int m = m0 + wv*4 + j;
        bf8 aA1 = *(const bf8*)(A1 + (size_t)m*512 + l15*32 + quad*8);
        f4 z = {0.f,0.f,0.f,0.f};
        f4 g = __builtin_amdgcn_mfma_f32_16x16x32_bf16(aA1, qbN, z, 0, 0, 0);
        uint2 ax = *(const uint2*)(adjPT + (size_t)m*8192 + (n0 + l15)*16 + quad*4);
        uint2 ay = *(const uint2*)(adjP  + (size_t)m*8192 + (n0 + l15)*16 + quad*4);
        float v;
        v = bf2f((u16)(ax.x & 0xffffu)) * g[0];
        v = fmaf(bf2f((u16)(ax.x >> 16)),     g[1], v);
        v = fmaf(bf2f((u16)(ax.y & 0xffffu)), g[2], v);
        v = fmaf(bf2f((u16)(ax.y >> 16)),     g[3], v);
        v = fmaf(bf2f((u16)(ay.x & 0xffffu)), qb4.x, v);
        v = fmaf(bf2f((u16)(ay.x >> 16)),     qb4.y, v);
        v = fmaf(bf2f((u16)(ay.y & 0xffffu)), qb4.z, v);
        v = fmaf(bf2f((u16)(ay.y >> 16)),     qb4.w, v);
        v += __shfl_xor(v, 16, 64);
        v += __shfl_xor(v, 32, 64);
        if (quad == 0) sL1[l15*17 + wv*4 + j] = v;
    }
    #pragma unroll
    for (int j = 0; j < 4; j++) {
        int n = n0 + wv*4 + j;
        bf8 aB1 = *(const bf8*)(B1 + (size_t)n*512 + l15*32 + quad*8);
        f4 z = {0.f,0.f,0.f,0.f};
        f4 h = __builtin_amdgcn_mfma_f32_16x16x32_bf16(aB1, qbM, z, 0, 0, 0);
        uint2 ax = *(const uint2*)(adjPT + (size_t)n*8192 + (m0 + l15)*16 + quad*4);
        uint2 ay = *(const uint2*)(adjP  + (size_t)n*8192 + (m0 + l15)*16 + quad*4);
        float v;
        v = bf2f((u16)(ax.x & 0xffffu)) * h[0];
        v = fmaf(bf2f((u16)(ax.x >> 16)),     h[1], v);
        v = fmaf(bf2f((u16)(ax.y & 0xffffu)), h[2], v);
        v = fmaf(bf2f((u16)(ax.y >> 16)),     h[3], v);
        v = fmaf(bf2f((u16)(ay.x & 0xffffu)), qa4.x, v);
        v = fmaf(bf2f((u16)(ay.x >> 16)),     qa4.y, v);
        v = fmaf(bf2f((u16)(ay.y & 0xffffu)), qa4.z, v);
        v = fmaf(bf2f((u16)(ay.y >> 16)),     qa4.w, v);
        v += __shfl_xor(v, 16, 64);
        v += __shfl_xor(v, 32, 64);
        if (quad == 0) sL2[l15*17 + wv*4 + j] = v;
    }
    __syncthreads();
    int row = tid >> 4, col = tid & 15;
    float v1 = sL1[row*17+col];
    float v2v = sL2[row*17+col];
    L1 [(size_t)(n0+row)*NNODE + m0 + col] = v1;
    L2T[(size_t)(m0+row)*NNODE + n0 + col] = v2v;

    // per-panel stats: reduce over the 16 cols (lanes within 16-lane group)
    float mx1 = v1, mx2 = v2v;
    #pragma unroll
    for (int o=1; o<16; o<<=1) {
        mx1 = fmaxf(mx1, __shfl_xor(mx1, o, 64));
        mx2 = fmaxf(mx2, __shfl_xor(mx2, o, 64));
    }
    float s1 = __expf(v1 - mx1), s2 = __expf(v2v - mx2);
    #pragma unroll
    for (int o=1; o<16; o<<=1) {
        s1 += __shfl_xor(s1, o, 64);
        s2 += __shfl_xor(s2, o, 64);
    }
    if (col == 0) {
        float2 st1; st1.x = mx1; st1.y = s1;
        float2 st2; st2.x = mx2; st2.y = s2;
        statsP[(size_t)(n0+row)*32 + blockIdx.x]         = st1;  // L1 rows
        statsP[(size_t)(NNODE + m0+row)*32 + blockIdx.y] = st2;  // L2T rows
    }
}

// ---------------------------------------------------------------------------
// K34: phase 0 merges 32 panel-stats per row; then W-chunk build (LDS,
// XOR-swizzled) + MFMA GEMM + u-fold, accumulated via fire-and-forget
// f32 atomics into temp[512][32], u1/v2[512][16]. No fences.
// ---------------------------------------------------------------------------
__global__ __launch_bounds__(256) void k_smx_gemm(
    const float* __restrict__ L1, const float* __restrict__ L2T,
    const u16* __restrict__ adjP, const u16* __restrict__ adjPT,
    const u16* __restrict__ A2T, const u16* __restrict__ B2T,
    const float2* __restrict__ statsP,
    float* __restrict__ temp, float* __restrict__ u1, float* __restrict__ v2)
{
    const int j0 = blockIdx.x * 16, kc = blockIdx.y, dir = blockIdx.z;
    const int tid = threadIdx.x;
    const int wv = tid >> 6, lane = tid & 63, l15 = lane & 15, quad = lane >> 4;
    const float* Lbase = dir ? L2T : L1;

    __shared__ alignas(16) u16 Wt[16*256];      // 8KB: W chunk, 16B-slot XOR swizzle
    __shared__ alignas(16) float redb[4][512];  // 8KB: cross-wave MFMA reduce
    __shared__ float2 sst[16];

    // ---- phase 0: merge 32 panel stats per row (16 threads per row) ----
    {
        int j = tid >> 4, pp = tid & 15;
        const float2* sp = statsP + (size_t)(dir*NNODE + j0 + j)*32;
        float2 a = sp[pp*2], b = sp[pp*2+1];
        float mx = fmaxf(a.x, b.x);
        float sm = a.y*__expf(a.x - mx) + b.y*__expf(b.x - mx);
        #pragma unroll
        for (int o=1; o<16; o<<=1) {
            float omx = __shfl_xor(mx, o, 64), osm = __shfl_xor(sm, o, 64);
            float nmx = fmaxf(mx, omx);
            sm = sm*__expf(mx - nmx) + osm*__expf(omx - nmx);
            mx = nmx;
        }
        if (pp == 0) { float2 st; st.x = mx; st.y = 1.0f/sm; sst[j] = st; }
    }
    __syncthreads();

    // ---- phase 1: W-chunk build + u partial (1 m-column per thread) ----
    {
        int j = tid >> 4, cb = tid & 15;
        int m = kc*16 + cb;                   // global m-column
        float2 st = sst[j];
        float s0 = __expf(Lbase[(size_t)(j0+j)*NNODE + m] - st.x) * st.y;

        const uint4* pp = (const uint4*)(adjP + (size_t)(j0+j)*8192 + m*16);
        float av[16]; unpack8(pp[0], av); unpack8(pp[1], av+8);
        u16 wo[16];
        #pragma unroll
        for (int e=0;e<16;e++) wo[e] = f2bf(s0*av[e]);
        #pragma unroll
        for (int q=0;q<2;q++) {
            int sl = (cb*2 + q) ^ (j & 7);    // swizzled 16B slot (32 slots/row)
            *(uint4*)&Wt[j*256 + sl*8] = pack8(wo + q*8);
        }

        const uint4* qq = (const uint4*)(adjPT + (size_t)(j0+j)*8192 + m*16);
        float tv[16]; unpack8(qq[0], tv); unpack8(qq[1], tv+8);
        float ut[16];
        #pragma unroll
        for (int t=0;t<16;t++) ut[t] = s0*tv[t];
        // exchange-and-halve fold over the 16 cb-lanes (xor 1,2,4,8)
        #pragma unroll
        for (int i=0;i<8;i++) {
            float v0 = (lane&1) ? ut[i] : ut[i+8];
            float r0 = __shfl_xor(v0, 1, 64);
            ut[i] = ((lane&1) ? ut[i+8] : ut[i]) + r0;
        }
        #pragma unroll
        for (int i=0;i<4;i++) {
            float v0 = (lane&2) ? ut[i] : ut[i+4];
            float r0 = __shfl_xor(v0, 2, 64);
            ut[i] = ((lane&2) ? ut[i+4] : ut[i]) + r0;
        }
        #pragma unroll
        for (int i=0;i<2;i++) {
            float v0 = (lane&4) ? ut[i] : ut[i+2];
            float r0 = __shfl_xor(v0, 4, 64);
            ut[i] = ((lane&4) ? ut[i+2] : ut[i]) + r0;
        }
        {
            float v0 = (lane&8) ? ut[0] : ut[1];
            float r0 = __shfl_xor(v0, 8, 64);
            ut[0] = ((lane&8) ? ut[1] : ut[0]) + r0;
        }
        int tm = ((cb&1)<<3) | ((cb&2)<<1) | ((cb&4)>>1) | ((cb&8)>>3);
        atomicAdd((dir ? v2 : u1) + (size_t)(j0+j)*TP + tm, ut[0]);
    }
    __syncthreads();

    // ---- phase 2: MFMA [16 j][256 k] x [256 k][32 d]; wave = k-eighth ----
    {
        const u16* Bmat = dir ? B2T : A2T;
        f4 acc0 = {0.f,0.f,0.f,0.f}, acc1 = {0.f,0.f,0.f,0.f};
        #pragma unroll
        for (int st2 = 0; st2 < 2; st2++) {
            int s = wv*2 + st2;               // 0..7
            bf8 afr = *(const bf8*)&Wt[l15*256 + (((s*4 + quad) ^ (l15 & 7)) << 3)];
            bf8 b0 = *(const bf8*)(Bmat + (size_t)(l15)*8192    + kc*256 + s*32 + quad*8);
            bf8 b1 = *(const bf8*)(Bmat + (size_t)(16+l15)*8192 + kc*256 + s*32 + quad*8);
            acc0 = __builtin_amdgcn_mfma_f32_16x16x32_bf16(afr, b0, acc0, 0, 0, 0);
            acc1 = __builtin_amdgcn_mfma_f32_16x16x32_bf16(afr, b1, acc1, 0, 0, 0);
        }
        #pragma unroll
        for (int r = 0; r < 4; r++) {
            redb[wv][      (quad*4+r)*16 + l15] = acc0[r];
            redb[wv][256 + (quad*4+r)*16 + l15] = acc1[r];
        }
    }
    __syncthreads();
    #pragma unroll
    for (int h = 0; h < 2; h++) {
        int o = tid + h*256;                 // 0..511 over (j,d)
        int jj = o >> 5, d = o & 31;
        int idx = (d >> 4)*256 + jj*16 + (d & 15);
        float v = redb[0][idx] + redb[1][idx] + redb[2][idx] + redb[3][idx];
        atomicAdd(&temp[(size_t)(j0 + jj)*DD + d], v);
    }
}

// ---------------------------------------------------------------------------
// K5: self terms (u1·B2T + v2·A2T) + lrelu; temp already complete.
// ---------------------------------------------------------------------------
__global__ __launch_bounds__(256) void k_final(
    const float* __restrict__ temp, const float* __restrict__ u1, const float* __restrict__ v2,
    const u16* __restrict__ A2T, const u16* __restrict__ B2T, float* __restrict__ out)
{
    int base = blockIdx.x * 256 + threadIdx.x;   // 0..16383 over 64 blocks
    int j = base >> 5, d = base & 31;
    float acc = temp[(size_t)j*DD + d];
    const uint4* pb2 = (const uint4*)(B2T + (size_t)d*8192 + j*16);
    const uint4* pa2 = (const uint4*)(A2T + (size_t)d*8192 + j*16);
    float bv[16], avv[16];
    unpack8(pb2[0], bv);  unpack8(pb2[1], bv+8);
    unpack8(pa2[0], avv); unpack8(pa2[1], avv+8);
    #pragma unroll
    for (int t = 0; t < 16; t++)
        acc += u1[(size_t)j*TP + t]*bv[t] + v2[(size_t)j*TP + t]*avv[t];
    out[(size_t)j*DD + d] = fmaxf(acc, 0.2f*acc);
}

// ---------------------------------------------------------------------------
extern "C" void kernel_launch(void* const* d_in, const int* in_sizes, int n_in,
                              void* d_out, int out_size, void* d_ws, size_t ws_size,
                              hipStream_t stream)
{
    (void)in_sizes; (void)n_in; (void)out_size; (void)ws_size;
    const float* x   = (const float*)d_in[0];
    const float* adj = (const float*)d_in[1];
    const float* W1  = (const float*)d_in[2];
    const float* W2  = (const float*)d_in[3];
    const float* W3  = (const float*)d_in[4];

    char* ws = (char*)d_ws;
    u16*   adjP  = (u16*)(ws);                   // 8 MB
    u16*   adjPT = (u16*)(ws + 0x800000);        // 8 MB
    u16*   A1    = (u16*)(ws + 0x1000000);       // 512 KB each
    u16*   B1    = (u16*)(ws + 0x1080000);
    u16*   A2T   = (u16*)(ws + 0x1100000);
    u16*   B2T   = (u16*)(ws + 0x1180000);
    u16*   Qb    = (u16*)(ws + 0x1200000);       // 32 KB
    float* QAd   = (float*)(ws + 0x1210000);
    float* QB    = (float*)(ws + 0x1220000);
    float* L1    = (float*)(ws + 0x1300000);     // 1 MB
    float* L2T   = (float*)(ws + 0x1400000);     // 1 MB
    float* temp  = (float*)(ws + 0x1500000);     // 64 KB accumulator
    float* u1    = (float*)(ws + 0x1510000);     // 32 KB
    float* v2    = (float*)(ws + 0x1520000);     // 32 KB
    float2* statsP=(float2*)(ws + 0x1530000);    // 256 KB: [1024 rows][32 panels]

    k_prep_adjp<<<896, 256, 0, stream>>>(x, W1, W2, W3, adj,
                                         A1, B1, A2T, B2T, Qb, QAd, QB, adjP, adjPT,
                                         temp, u1, v2);
    k_logits<<<dim3(32,32), 256, 0, stream>>>(Qb, A1, B1, adjP, adjPT, QAd, QB,
                                              L1, L2T, statsP);
    k_smx_gemm<<<dim3(32,32,2), 256, 0, stream>>>(L1, L2T, adjP, adjPT, A2T, B2T,
                                                  statsP, temp, u1, v2);
    k_final<<<64, 256, 0, stream>>>(temp, u1, v2, A2T, B2T, (float*)d_out);
}

// Round 6
// 101.682 us; speedup vs baseline: 3.3028x; 1.0049x over previous
//
#include <hip/hip_runtime.h>
#include <hip/hip_bf16.h>

#define NNODE 512
#define CCH   16
#define TT    15
#define TP    16
#define HH    32
#define DD    32

typedef unsigned short u16;
typedef unsigned int   u32;
typedef short bf8 __attribute__((ext_vector_type(8)));   // 8 bf16 = 4 VGPR (MFMA A/B frag)
typedef float f4  __attribute__((ext_vector_type(4)));   // MFMA C/D frag

__device__ __forceinline__ float bf2f(u16 v) {
    union { u32 u; float f; } x; x.u = ((u32)v) << 16; return x.f;
}
__device__ __forceinline__ u16 f2bf(float f) {
    union { float f; u32 u; } x; x.f = f;
    u32 u = x.u;
    return (u16)((u + 0x7FFFu + ((u >> 16) & 1u)) >> 16);
}
__device__ __forceinline__ void unpack8(uint4 p, float* o) {
    o[0]=bf2f((u16)(p.x & 0xffffu)); o[1]=bf2f((u16)(p.x >> 16));
    o[2]=bf2f((u16)(p.y & 0xffffu)); o[3]=bf2f((u16)(p.y >> 16));
    o[4]=bf2f((u16)(p.z & 0xffffu)); o[5]=bf2f((u16)(p.z >> 16));
    o[6]=bf2f((u16)(p.w & 0xffffu)); o[7]=bf2f((u16)(p.w >> 16));
}
__device__ __forceinline__ uint4 pack8(const u16* v) {
    return make_uint4((u32)v[0]|((u32)v[1]<<16), (u32)v[2]|((u32)v[3]<<16),
                      (u32)v[4]|((u32)v[5]<<16), (u32)v[6]|((u32)v[7]<<16));
}

// ---------------------------------------------------------------------------
// K1: blocks 0..511: per-node prep. blocks 512..1023: adjacency 16x32 tiles
//     (2 blocks/CU for this phase). blocks 1024..1151: zero temp/u1/v2.
// ---------------------------------------------------------------------------
__global__ __launch_bounds__(256) void k_prep_adjp(
    const float* __restrict__ x, const float* __restrict__ W1,
    const float* __restrict__ W2, const float* __restrict__ W3,
    const float* __restrict__ adj,
    u16* __restrict__ A1, u16* __restrict__ B1,
    u16* __restrict__ A2T, u16* __restrict__ B2T,
    u16* __restrict__ Qb, float* __restrict__ QAd, float* __restrict__ QB,
    u16* __restrict__ adjP, u16* __restrict__ adjPT,
    float* __restrict__ temp, float* __restrict__ u1, float* __restrict__ v2)
{
    int tid = threadIdx.x;
    if (blockIdx.x >= 1024) {                // zero accumulators
        int idx = (blockIdx.x - 1024) * 256 + tid;
        if (idx < 16384) temp[idx] = 0.f;
        else if (idx < 24576) u1[idx - 16384] = 0.f;
        else if (idx < 32768) v2[idx - 24576] = 0.f;
        return;
    }
    if (blockIdx.x < 512) {
        int n = blockIdx.x;
        __shared__ alignas(16) float xs[CCH];
        __shared__ alignas(16) float A1row[512], B1row[512];
        __shared__ alignas(16) float A2row[512], B2row[512];
        __shared__ alignas(16) float Qs[HH];
        if (tid < CCH) xs[tid] = x[n*CCH + tid];
        __syncthreads();
        float xr[CCH];
        #pragma unroll
        for (int i=0;i<CCH;i++) xr[i]=xs[i];
        #pragma unroll
        for (int rep=0; rep<2; rep++) {
            int c = tid + rep*256;
            float a1=0.f,b1=0.f,a2=0.f,b2=0.f;
            #pragma unroll
            for (int i=0;i<CCH;i++) {
                a1 += xr[i]*W1[i*512 + c];
                b1 += xr[i]*W1[(CCH+i)*512 + c];
                a2 += xr[i]*W2[i*512 + c];
                b2 += xr[i]*W2[(CCH+i)*512 + c];
            }
            A1[(size_t)n*512 + c]=f2bf(a1); B1[(size_t)n*512 + c]=f2bf(b1);
            A1row[c]=a1; B1row[c]=b1; A2row[c]=a2; B2row[c]=b2;
        }
        if (tid < HH) {
            float q=0.f;
            #pragma unroll
            for (int i=0;i<CCH;i++) q += xr[i]*W3[i*HH + tid];
            Qs[tid]=q; Qb[(size_t)n*HH + tid]=f2bf(q);
        }
        __syncthreads();
        if (tid < TP) {
            float qa=0.f, qb=0.f;
            #pragma unroll
            for (int h=0;h<HH;h++) { qa += Qs[h]*A1row[tid*HH+h]; qb += Qs[h]*B1row[tid*HH+h]; }
            QAd[(size_t)n*TP + tid]=qa; QB[(size_t)n*TP + tid]=qb;
        }
        {   // A2T/B2T: [d][n*16+t]; coalesced u32 stores
            int d = tid >> 3, t0 = (tid & 7) * 2;
            u32 pa = (u32)f2bf(A2row[t0*32 + d]) | ((u32)f2bf(A2row[(t0+1)*32 + d]) << 16);
            u32 pb = (u32)f2bf(B2row[t0*32 + d]) | ((u32)f2bf(B2row[(t0+1)*32 + d]) << 16);
            *(u32*)(A2T + (size_t)d*8192 + n*16 + t0) = pa;
            *(u32*)(B2T + (size_t)d*8192 + n*16 + t0) = pb;
        }
    } else {
        int b = blockIdx.x - 512;            // 0..511: 16n x 32m tile
        int n0 = (b >> 4) * 16, m0 = (b & 15) * 32;
        __shared__ alignas(16) u16 s[16*520];  // stride 520 (1040B=65*16)
        #pragma unroll
        for (int i = 0; i < 30; i++) {
            int e = tid + i*256;             // 0..7679
            int nl = e / 480; int rem = e - nl*480;
            int ml = rem / 15; int t = rem - ml*15;
            float v = adj[((size_t)(n0+nl)*512 + (m0+ml))*TT + t];
            s[nl*520 + ml*16 + t] = f2bf(v);
        }
        #pragma unroll
        for (int i = 0; i < 2; i++) {
            int e = tid + i*256; int nl = e >> 5, ml = e & 31;
            s[nl*520 + ml*16 + 15] = ((n0+nl) == (m0+ml)) ? (u16)0x3F80 : (u16)0;
        }
        __syncthreads();
        #pragma unroll
        for (int i = 0; i < 4; i++) {        // adjP: 16 rows x 1KB
            int c = tid + i*256;
            int nl = c >> 6, off = (c & 63) * 8;
            uint4 vv = *(const uint4*)(s + nl*520 + off);
            *(uint4*)(adjP + (size_t)(n0+nl)*8192 + m0*16 + off) = vv;
        }
        #pragma unroll
        for (int i = 0; i < 4; i++) {        // adjPT: 32 rows x 512B (transposed)
            int c = tid + i*256;
            int ml = c >> 5, nlh = c & 31, nl = nlh >> 1, half = nlh & 1;
            uint4 vv = *(const uint4*)(s + nl*520 + ml*16 + half*8);
            *(uint4*)(adjPT + (size_t)(m0+ml)*8192 + (n0+nl)*16 + half*8) = vv;
        }
    }
}

// ---------------------------------------------------------------------------
// K2: fused logits, 16m x 32n strip per block (A1 frags + Q prologue reused
// across 2 n-tiles) + per-panel softmax stats. grid (32 m-tiles, 16 n-pairs).
// ---------------------------------------------------------------------------
__global__ __launch_bounds__(256) void k_logits(
    const u16* __restrict__ Qb, const u16* __restrict__ A1, const u16* __restrict__ B1,
    const u16* __restrict__ adjP, const u16* __restrict__ adjPT,
    const float* __restrict__ QAd, const float* __restrict__ QB,
    float* __restrict__ L1, float* __restrict__ L2T,
    float2* __restrict__ statsP)
{
    const int m0 = blockIdx.x * 16, n0 = blockIdx.y * 32;
    const int tid = threadIdx.x;
    const int wv = tid >> 6, lane = tid & 63, l15 = lane & 15, quad = lane >> 4;
    __shared__ alignas(16) float sL1[32*17];   // [n-local 32][m-local 16]
    __shared__ alignas(16) float sL2[16*33];   // [m-local 16][n-local 32]

    bf8 qbN0 = *(const bf8*)(Qb + (size_t)(n0 + l15)*32 + quad*8);
    bf8 qbN1 = *(const bf8*)(Qb + (size_t)(n0 + 16 + l15)*32 + quad*8);
    bf8 qbM  = *(const bf8*)(Qb + (size_t)(m0 + l15)*32 + quad*8);
    float4 qb40 = *(const float4*)(QB  + (size_t)(n0 + l15)*TP + quad*4);
    float4 qb41 = *(const float4*)(QB  + (size_t)(n0 + 16 + l15)*TP + quad*4);
    float4 qa4  = *(const float4*)(QAd + (size_t)(m0 + l15)*TP + quad*4);

    #pragma unroll
    for (int j = 0; j < 4; j++) {
        int m = m0 + wv*4 + j;
        bf8 aA1 = *(const bf8*)(A1 + (size_t)m*512 + l15*32 + quad*8);
        f4 z = {0.f,0.f,0.f,0.f};
        f4 g0 = __builtin_amdgcn_mfma_f32_16x16x32_bf16(aA1, qbN0, z, 0, 0, 0);
        f4 g1 = __builtin_amdgcn_mfma_f32_16x16x32_bf16(aA1, qbN1, z, 0, 0, 0);
        {   // n-tile 0
            uint2 ax = *(const uint2*)(adjPT + (size_t)m*8192 + (n0 + l15)*16 + quad*4);
            uint2 ay = *(const uint2*)(adjP  + (size_t)m*8192 + (n0 + l15)*16 + quad*4);
            float v;
            v = bf2f((u16)(ax.x & 0xffffu)) * g0[0];
            v = fmaf(bf2f((u16)(ax.x >> 16)),     g0[1], v);
            v = fmaf(bf2f((u16)(ax.y & 0xffffu)), g0[2], v);
            v = fmaf(bf2f((u16)(ax.y >> 16)),     g0[3], v);
            v = fmaf(bf2f((u16)(ay.x & 0xffffu)), qb40.x, v);
            v = fmaf(bf2f((u16)(ay.x >> 16)),     qb40.y, v);
            v = fmaf(bf2f((u16)(ay.y & 0xffffu)), qb40.z, v);
            v = fmaf(bf2f((u16)(ay.y >> 16)),     qb40.w, v);
            v += __shfl_xor(v, 16, 64);
            v += __shfl_xor(v, 32, 64);
            if (quad == 0) sL1[l15*17 + wv*4 + j] = v;
        }
        {   // n-tile 1
            uint2 ax = *(const uint2*)(adjPT + (size_t)m*8192 + (n0 + 16 + l15)*16 + quad*4);
            uint2 ay = *(const uint2*)(adjP  + (size_t)m*8192 + (n0 + 16 + l15)*16 + quad*4);
            float v;
            v = bf2f((u16)(ax.x & 0xffffu)) * g1[0];
            v = fmaf(bf2f((u16)(ax.x >> 16)),     g1[1], v);
            v = fmaf(bf2f((u16)(ax.y & 0xffffu)), g1[2], v);
            v = fmaf(bf2f((u16)(ax.y >> 16)),     g1[3], v);
            v = fmaf(bf2f((u16)(ay.x & 0xffffu)), qb41.x, v);
            v = fmaf(bf2f((u16)(ay.x >> 16)),     qb41.y, v);
            v = fmaf(bf2f((u16)(ay.y & 0xffffu)), qb41.z, v);
            v = fmaf(bf2f((u16)(ay.y >> 16)),     qb41.w, v);
            v += __shfl_xor(v, 16, 64);
            v += __shfl_xor(v, 32, 64);
            if (quad == 0) sL1[(16 + l15)*17 + wv*4 + j] = v;
        }
    }
    #pragma unroll
    for (int j2 = 0; j2 < 8; j2++) {
        int n = n0 + wv*8 + j2;
        bf8 aB1 = *(const bf8*)(B1 + (size_t)n*512 + l15*32 + quad*8);
        f4 z = {0.f,0.f,0.f,0.f};
        f4 h = __builtin_amdgcn_mfma_f32_16x16x32_bf16(aB1, qbM, z, 0, 0, 0);
        uint2 ax = *(const uint2*)(adjPT + (size_t)n*8192 + (m0 + l15)*16 + quad*4);
        uint2 ay = *(const uint2*)(adjP  + (size_t)n*8192 + (m0 + l15)*16 + quad*4);
        float v;
        v = bf2f((u16)(ax.x & 0xffffu)) * h[0];
        v = fmaf(bf2f((u16)(ax.x >> 16)),     h[1], v);
        v = fmaf(bf2f((u16)(ax.y & 0xffffu)), h[2], v);
        v = fmaf(bf2f((u16)(ax.y >> 16)),     h[3], v);
        v = fmaf(bf2f((u16)(ay.x & 0xffffu)), qa4.x, v);
        v = fmaf(bf2f((u16)(ay.x >> 16)),     qa4.y, v);
        v = fmaf(bf2f((u16)(ay.y & 0xffffu)), qa4.z, v);
        v = fmaf(bf2f((u16)(ay.y >> 16)),     qa4.w, v);
        v += __shfl_xor(v, 16, 64);
        v += __shfl_xor(v, 32, 64);
        if (quad == 0) sL2[l15*33 + wv*8 + j2] = v;
    }
    __syncthreads();

    int row = tid >> 4, col = tid & 15;
    #pragma unroll
    for (int rr = 0; rr < 2; rr++) {         // L1: 32 n-rows x 16 m-cols
        int r = rr*16 + row;
        float v1 = sL1[r*17 + col];
        L1[(size_t)(n0+r)*NNODE + m0 + col] = v1;
        float mx = v1;
        #pragma unroll
        for (int o=1; o<16; o<<=1) mx = fmaxf(mx, __shfl_xor(mx, o, 64));
        float s1 = __expf(v1 - mx);
        #pragma unroll
        for (int o=1; o<16; o<<=1) s1 += __shfl_xor(s1, o, 64);
        if (col == 0) { float2 st; st.x = mx; st.y = s1;
                        statsP[(size_t)(n0+r)*32 + blockIdx.x] = st; }
    }
    #pragma unroll
    for (int cc = 0; cc < 2; cc++) {         // L2T: 16 m-rows x 32 n-cols
        int c2 = cc*16 + col;
        float v2v = sL2[row*33 + c2];
        L2T[(size_t)(m0+row)*NNODE + n0 + c2] = v2v;
        float mx = v2v;
        #pragma unroll
        for (int o=1; o<16; o<<=1) mx = fmaxf(mx, __shfl_xor(mx, o, 64));
        float s2 = __expf(v2v - mx);
        #pragma unroll
        for (int o=1; o<16; o<<=1) s2 += __shfl_xor(s2, o, 64);
        if (col == 0) { float2 st; st.x = mx; st.y = s2;
                        statsP[(size_t)(NNODE + m0+row)*32 + blockIdx.y*2 + cc] = st; }
    }
}

// ---------------------------------------------------------------------------
// K34: BOTH directions per block (adjP/adjPT loaded once, both W-chunks
// built, both accumulated into the same MFMA acc). grid (32 j0, 32 kc).
// ---------------------------------------------------------------------------
__global__ __launch_bounds__(256) void k_smx_gemm(
    const float* __restrict__ L1, const float* __restrict__ L2T,
    const u16* __restrict__ adjP, const u16* __restrict__ adjPT,
    const u16* __restrict__ A2T, const u16* __restrict__ B2T,
    const float2* __restrict__ statsP,
    float* __restrict__ temp, float* __restrict__ u1, float* __restrict__ v2)
{
    const int j0 = blockIdx.x * 16, kc = blockIdx.y;
    const int tid = threadIdx.x;
    const int wv = tid >> 6, lane = tid & 63, l15 = lane & 15, quad = lane >> 4;

    __shared__ alignas(16) u16 Wt0[16*256];     // 8KB each, XOR-swizzled 16B slots
    __shared__ alignas(16) u16 Wt1[16*256];
    __shared__ alignas(16) float redb[4][512];
    __shared__ float2 sst0[16], sst1[16];

    // ---- phase 0: merge 32 panel stats per row, both dirs ----
    {
        int j = tid >> 4, pp = tid & 15;
        {
            const float2* sp = statsP + (size_t)(j0 + j)*32;
            float2 a = sp[pp*2], b = sp[pp*2+1];
            float mx = fmaxf(a.x, b.x);
            float sm = a.y*__expf(a.x - mx) + b.y*__expf(b.x - mx);
            #pragma unroll
            for (int o=1; o<16; o<<=1) {
                float omx = __shfl_xor(mx, o, 64), osm = __shfl_xor(sm, o, 64);
                float nmx = fmaxf(mx, omx);
                sm = sm*__expf(mx - nmx) + osm*__expf(omx - nmx);
                mx = nmx;
            }
            if (pp == 0) { float2 st; st.x = mx; st.y = 1.0f/sm; sst0[j] = st; }
        }
        {
            const float2* sp = statsP + (size_t)(NNODE + j0 + j)*32;
            float2 a = sp[pp*2], b = sp[pp*2+1];
            float mx = fmaxf(a.x, b.x);
            float sm = a.y*__expf(a.x - mx) + b.y*__expf(b.x - mx);
            #pragma unroll
            for (int o=1; o<16; o<<=1) {
                float omx = __shfl_xor(mx, o, 64), osm = __shfl_xor(sm, o, 64);
                float nmx = fmaxf(mx, omx);
                sm = sm*__expf(mx - nmx) + osm*__expf(omx - nmx);
                mx = nmx;
            }
            if (pp == 0) { float2 st; st.x = mx; st.y = 1.0f/sm; sst1[j] = st; }
        }
    }
    __syncthreads();

    // ---- phase 1: both W-chunks + both u-folds (adjP/adjPT read ONCE) ----
    {
        int j = tid >> 4, cb = tid & 15;
        int m = kc*16 + cb;
        float2 st0 = sst0[j], st1 = sst1[j];
        float s0 = __expf(L1 [(size_t)(j0+j)*NNODE + m] - st0.x) * st0.y;
        float s1 = __expf(L2T[(size_t)(j0+j)*NNODE + m] - st1.x) * st1.y;

        const uint4* pp4 = (const uint4*)(adjP + (size_t)(j0+j)*8192 + m*16);
        float av[16]; unpack8(pp4[0], av); unpack8(pp4[1], av+8);
        u16 wo0[16], wo1[16];
        #pragma unroll
        for (int e=0;e<16;e++) { wo0[e] = f2bf(s0*av[e]); wo1[e] = f2bf(s1*av[e]); }
        #pragma unroll
        for (int q=0;q<2;q++) {
            int sl = (cb*2 + q) ^ (j & 7);    // swizzled 16B slot (32 slots/row)
            *(uint4*)&Wt0[j*256 + sl*8] = pack8(wo0 + q*8);
            *(uint4*)&Wt1[j*256 + sl*8] = pack8(wo1 + q*8);
        }

        const uint4* qq = (const uint4*)(adjPT + (size_t)(j0+j)*8192 + m*16);
        float tv[16]; unpack8(qq[0], tv); unpack8(qq[1], tv+8);
        float ut0[16], ut1[16];
        #pragma unroll
        for (int t=0;t<16;t++) { ut0[t] = s0*tv[t]; ut1[t] = s1*tv[t]; }
        // exchange-and-halve fold (xor 1,2,4,8) -- both dirs
        #pragma unroll
        for (int i=0;i<8;i++) {
            float a0 = (lane&1) ? ut0[i] : ut0[i+8];
            float a1 = (lane&1) ? ut1[i] : ut1[i+8];
            float r0 = __shfl_xor(a0, 1, 64), r1 = __shfl_xor(a1, 1, 64);
            ut0[i] = ((lane&1) ? ut0[i+8] : ut0[i]) + r0;
            ut1[i] = ((lane&1) ? ut1[i+8] : ut1[i]) + r1;
        }
        #pragma unroll
        for (int i=0;i<4;i++) {
            float a0 = (lane&2) ? ut0[i] : ut0[i+4];
            float a1 = (lane&2) ? ut1[i] : ut1[i+4];
            float r0 = __shfl_xor(a0, 2, 64), r1 = __shfl_xor(a1, 2, 64);
            ut0[i] = ((lane&2) ? ut0[i+4] : ut0[i]) + r0;
            ut1[i] = ((lane&2) ? ut1[i+4] : ut1[i]) + r1;
        }
        #pragma unroll
        for (int i=0;i<2;i++) {
            float a0 = (lane&4) ? ut0[i] : ut0[i+2];
            float a1 = (lane&4) ? ut1[i] : ut1[i+2];
            float r0 = __shfl_xor(a0, 4, 64), r1 = __shfl_xor(a1, 4, 64);
            ut0[i] = ((lane&4) ? ut0[i+2] : ut0[i]) + r0;
            ut1[i] = ((lane&4) ? ut1[i+2] : ut1[i]) + r1;
        }
        {
            float a0 = (lane&8) ? ut0[0] : ut0[1];
            float a1 = (lane&8) ? ut1[0] : ut1[1];
            float r0 = __shfl_xor(a0, 8, 64), r1 = __shfl_xor(a1, 8, 64);
            ut0[0] = ((lane&8) ? ut0[1] : ut0[0]) + r0;
            ut1[0] = ((lane&8) ? ut1[1] : ut1[0]) + r1;
        }
        int tm = ((cb&1)<<3) | ((cb&2)<<1) | ((cb&4)>>1) | ((cb&8)>>3);
        atomicAdd(u1 + (size_t)(j0+j)*TP + tm, ut0[0]);
        atomicAdd(v2 + (size_t)(j0+j)*TP + tm, ut1[0]);
    }
    __syncthreads();

    // ---- phase 2: temp[j][d] += Wt0·A2T + Wt1·B2T (same acc) ----
    {
        f4 acc0 = {0.f,0.f,0.f,0.f}, acc1 = {0.f,0.f,0.f,0.f};
        #pragma unroll
        for (int st2 = 0; st2 < 2; st2++) {
            int s = wv*2 + st2;               // 0..7
            int wslot = ((s*4 + quad) ^ (l15 & 7)) << 3;
            bf8 afr0 = *(const bf8*)&Wt0[l15*256 + wslot];
            bf8 afr1 = *(const bf8*)&Wt1[l15*256 + wslot];
            int kt = kc*256 + s*32 + quad*8;
            bf8 a20 = *(const bf8*)(A2T + (size_t)(l15)*8192    + kt);
            bf8 a21 = *(const bf8*)(A2T + (size_t)(16+l15)*8192 + kt);
            bf8 b20 = *(const bf8*)(B2T + (size_t)(l15)*8192    + kt);
            bf8 b21 = *(const bf8*)(B2T + (size_t)(16+l15)*8192 + kt);
            acc0 = __builtin_amdgcn_mfma_f32_16x16x32_bf16(afr0, a20, acc0, 0, 0, 0);
            acc0 = __builtin_amdgcn_mfma_f32_16x16x32_bf16(afr1, b20, acc0, 0, 0, 0);
            acc1 = __builtin_amdgcn_mfma_f32_16x16x32_bf16(afr0, a21, acc1, 0, 0, 0);
            acc1 = __builtin_amdgcn_mfma_f32_16x16x32_bf16(afr1, b21, acc1, 0, 0, 0);
        }
        #pragma unroll
        for (int r = 0; r < 4; r++) {
            redb[wv][      (quad*4+r)*16 + l15] = acc0[r];
            redb[wv][256 + (quad*4+r)*16 + l15] = acc1[r];
        }
    }
    __syncthreads();
    #pragma unroll
    for (int h = 0; h < 2; h++) {
        int o = tid + h*256;                 // 0..511 over (j,d)
        int jj = o >> 5, d = o & 31;
        int idx = (d >> 4)*256 + jj*16 + (d & 15);
        float v = redb[0][idx] + redb[1][idx] + redb[2][idx] + redb[3][idx];
        atomicAdd(&temp[(size_t)(j0 + jj)*DD + d], v);
    }
}

// ---------------------------------------------------------------------------
// K5: self terms (u1·B2T + v2·A2T) + lrelu; temp already complete.
// ---------------------------------------------------------------------------
__global__ __launch_bounds__(256) void k_final(
    const float* __restrict__ temp, const float* __restrict__ u1, const float* __restrict__ v2,
    const u16* __restrict__ A2T, const u16* __restrict__ B2T, float* __restrict__ out)
{
    int base = blockIdx.x * 256 + threadIdx.x;   // 0..16383 over 64 blocks
    int j = base >> 5, d = base & 31;
    float acc = temp[(size_t)j*DD + d];
    const uint4* pb2 = (const uint4*)(B2T + (size_t)d*8192 + j*16);
    const uint4* pa2 = (const uint4*)(A2T + (size_t)d*8192 + j*16);
    float bv[16], avv[16];
    unpack8(pb2[0], bv);  unpack8(pb2[1], bv+8);
    unpack8(pa2[0], avv); unpack8(pa2[1], avv+8);
    #pragma unroll
    for (int t = 0; t < 16; t++)
        acc += u1[(size_t)j*TP + t]*bv[t] + v2[(size_t)j*TP + t]*avv[t];
    out[(size_t)j*DD + d] = fmaxf(acc, 0.2f*acc);
}

// ---------------------------------------------------------------------------
extern "C" void kernel_launch(void* const* d_in, const int* in_sizes, int n_in,
                              void* d_out, int out_size, void* d_ws, size_t ws_size,
                              hipStream_t stream)
{
    (void)in_sizes; (void)n_in; (void)out_size; (void)ws_size;
    const float* x   = (const float*)d_in[0];
    const float* adj = (const float*)d_in[1];
    const float* W1  = (const float*)d_in[2];
    const float* W2  = (const float*)d_in[3];
    const float* W3  = (const float*)d_in[4];

    char* ws = (char*)d_ws;
    u16*   adjP  = (u16*)(ws);                   // 8 MB
    u16*   adjPT = (u16*)(ws + 0x800000);        // 8 MB
    u16*   A1    = (u16*)(ws + 0x1000000);       // 512 KB each
    u16*   B1    = (u16*)(ws + 0x1080000);
    u16*   A2T   = (u16*)(ws + 0x1100000);
    u16*   B2T   = (u16*)(ws + 0x1180000);
    u16*   Qb    = (u16*)(ws + 0x1200000);       // 32 KB
    float* QAd   = (float*)(ws + 0x1210000);
    float* QB    = (float*)(ws + 0x1220000);
    float* L1    = (float*)(ws + 0x1300000);     // 1 MB
    float* L2T   = (float*)(ws + 0x1400000);     // 1 MB
    float* temp  = (float*)(ws + 0x1500000);     // 64 KB accumulator
    float* u1    = (float*)(ws + 0x1510000);     // 32 KB
    float* v2    = (float*)(ws + 0x1520000);     // 32 KB
    float2* statsP=(float2*)(ws + 0x1530000);    // 256 KB: [1024 rows][32 panels]

    k_prep_adjp<<<1152, 256, 0, stream>>>(x, W1, W2, W3, adj,
                                          A1, B1, A2T, B2T, Qb, QAd, QB, adjP, adjPT,
                                          temp, u1, v2);
    k_logits<<<dim3(32,16), 256, 0, stream>>>(Qb, A1, B1, adjP, adjPT, QAd, QB,
                                              L1, L2T, statsP);
    k_smx_gemm<<<dim3(32,32), 256, 0, stream>>>(L1, L2T, adjP, adjPT, A2T, B2T,
                                                statsP, temp, u1, v2);
    k_final<<<64, 256, 0, stream>>>(temp, u1, v2, A2T, B2T, (float*)d_out);
}